// Round 15
// baseline (270.139 us; speedup 1.0000x reference)
//
#include <hip/hip_runtime.h>
#include <hip/hip_bf16.h>
#include <stdint.h>

#define L_DIM 384
#define MD    256      // M_DIM
#define CC    32       // C
#define ZD    128      // Z_DIM
#define NB    512      // N (batch) = K of the big GEMM
#define K2    1024     // C*C
#define MROWS 12288    // L*C

typedef __attribute__((ext_vector_type(4)))  float f32x4;
typedef __attribute__((ext_vector_type(8)))  short bf16x8;

#define PRIO1() __builtin_amdgcn_s_setprio(1)
#define PRIO0() __builtin_amdgcn_s_setprio(0)

__device__ __forceinline__ unsigned short f2bf(float x) {
    union { float f; unsigned u; } v; v.f = x;
    unsigned r = v.u + 0x7fffu + ((v.u >> 16) & 1u);   // round-to-nearest-even
    return (unsigned short)(r >> 16);
}

__device__ __forceinline__ uint2 pack4(unsigned short a, unsigned short b,
                                       unsigned short c, unsigned short d) {
    uint2 r; r.x = (unsigned)a | ((unsigned)b << 16);
    r.y = (unsigned)c | ((unsigned)d << 16); return r;
}

// HW packed f32->bf16 (RNE): 2 converts in 1 instruction
__device__ __forceinline__ unsigned cvtpk(float lo, float hi) {
    unsigned r;
    asm("v_cvt_pk_bf16_f32 %0, %1, %2" : "=v"(r) : "v"(lo), "v"(hi));
    return r;
}

// ---------------------------------------------------------------------------
// prep: w3 -> MFMA B-fragment order w3frag[ks][zg][lane][8], k2' = b*32+a
// (b-major so op tile writes vectorize). w1/w2 -> wfrag for ln_proj.
__global__ __launch_bounds__(256) void prep_kernel(
    const float* __restrict__ w1, const float* __restrict__ w2,
    const float* __restrict__ w3,
    unsigned short* __restrict__ w3frag, unsigned short* __restrict__ wfrag)
{
    int idx = blockIdx.x * 256 + threadIdx.x;          // 147456 total
    if (idx < 131072) {
        int e = idx & 7, lane = (idx >> 3) & 63, zg = (idx >> 9) & 7, ks = idx >> 12;
        int k2p = ks * 32 + ((lane >> 4) << 3) + e;    // k2' = b*32 + a
        int wrow = (k2p & 31) * 32 + (k2p >> 5);       // = a*32 + b
        int z  = zg * 16 + (lane & 15);
        w3frag[idx] = f2bf(w3[(size_t)wrow * ZD + z]);
    } else {
        int j = idx - 131072;                           // 16384
        int e = j & 7, lane = (j >> 3) & 63, nf = (j >> 9) & 3, ks = j >> 11;
        int c = nf * 16 + (lane & 15);
        int d = ks * 32 + ((lane >> 4) << 3) + e;
        float v = (c < CC) ? w2[d * CC + c] : w1[d * CC + (c - CC)];
        wfrag[j] = f2bf(v);
    }
}

// ---------------------------------------------------------------------------
// Kernel A: LayerNorm + dual projection via MFMA.
// BOTH At and Bt written in 16x16-MFMA fragment order [frag][kc][lane][8]
// (R6/R12-verified layout): frag = row/16, lane = (row&15) + 16*((n>>3)&3),
// elem = n&7, kc = n>>5.
__global__ __launch_bounds__(256, 4) void ln_proj_kernel(
    const float* __restrict__ mm, const float* __restrict__ gamma, const float* __restrict__ beta,
    const unsigned short* __restrict__ wfrag,
    const float* __restrict__ b1, const float* __restrict__ b2,
    unsigned short* __restrict__ At, unsigned short* __restrict__ Bt)
{
    __shared__ alignas(16) char o_b[32768];            // [64 rows][512 B] swizzled

    const int tid = threadIdx.x, wv = tid >> 6, lane = tid & 63;
    const int l0 = blockIdx.y * 2;
    const int n0 = blockIdx.x * 32;

    const int l_loc = wv >> 1;
    const int nbase = (wv & 1) << 4;
    const int l_g = l0 + l_loc;
    f32x4 g4 = *(const f32x4*)(gamma + lane * 4);
    f32x4 e4 = *(const f32x4*)(beta + lane * 4);

    #pragma unroll 4
    for (int r = 0; r < 16; ++r) {
        int row_loc = wv * 16 + r;
        int n_g = n0 + nbase + r;
        const float* src = mm + ((size_t)n_g * L_DIM + l_g) * MD + lane * 4;
        f32x4 x = *(const f32x4*)src;
        float s  = x[0] + x[1] + x[2] + x[3];
        float s2 = x[0]*x[0] + x[1]*x[1] + x[2]*x[2] + x[3]*x[3];
        #pragma unroll
        for (int off = 32; off > 0; off >>= 1) {
            s  += __shfl_xor(s,  off);
            s2 += __shfl_xor(s2, off);
        }
        float mu  = s * (1.0f / MD);
        float var = s2 * (1.0f / MD) - mu * mu;
        float rs  = rsqrtf(var + 1e-5f);
        unsigned short o0 = f2bf((x[0] - mu) * rs * g4[0] + e4[0]);
        unsigned short o1 = f2bf((x[1] - mu) * rs * g4[1] + e4[1]);
        unsigned short o2 = f2bf((x[2] - mu) * rs * g4[2] + e4[2]);
        unsigned short o3 = f2bf((x[3] - mu) * rs * g4[3] + e4[3]);
        *(uint2*)(o_b + row_loc * 512 + ((lane * 8) ^ ((row_loc & 7) << 4))) = pack4(o0, o1, o2, o3);
    }
    // wave-private rows -> no barrier needed

    f32x4 acc[4] = {{0,0,0,0},{0,0,0,0},{0,0,0,0},{0,0,0,0}};
    const int lrow = lane & 15;
    const int kq16 = (lane >> 4) << 4;
    const int arow = wv * 16 + lrow;
    #pragma unroll
    for (int ks = 0; ks < 8; ++ks) {
        bf16x8 a = *(const bf16x8*)(o_b + arow * 512 + ((ks * 64 + kq16) ^ ((arow & 7) << 4)));
        #pragma unroll
        for (int nf = 0; nf < 4; ++nf) {
            bf16x8 b = *(const bf16x8*)(wfrag + (size_t)((ks * 4 + nf) * 64 + lane) * 8);
            acc[nf] = __builtin_amdgcn_mfma_f32_16x16x32_bf16(a, b, acc[nf], 0, 0, 0);
        }
    }

    const int rr0 = wv * 16 + ((lane >> 4) << 2);
    const int n_gw = n0 + (rr0 & 31);
    const int l_gw = l0 + (rr0 >> 5);
    #pragma unroll
    for (int nf = 0; nf < 4; ++nf) {
        int c = nf * 16 + lrow;
        float bias = (c < CC) ? b2[c] : b1[c - CC];
        uint2 pk = pack4(f2bf(acc[nf][0] + bias), f2bf(acc[nf][1] + bias),
                         f2bf(acc[nf][2] + bias), f2bf(acc[nf][3] + bias));
        int c31 = c & 31;
        int f = l_gw * 2 + (c31 >> 4);                 // fragment index (row/16)
        int lanep = (c31 & 15) + (((n_gw >> 3) & 3) << 4);
        size_t addr = ((size_t)(f * 16 + (n_gw >> 5)) * 64 + lanep) * 8 + (n_gw & 7);
        *(uint2*)(((c < CC) ? At : Bt) + addr) = pk;
    }
}

// ---------------------------------------------------------------------------
// Kernel B: 256x256 op-tile GEMM, ZERO-SYNC main loop (R12/R14 winner):
// saddr-form loads (readfirstlane bases), nontemporal B loads (no L1
// allocate: B lines are 2-wave-dead, preserving L1 for the 4-way-shared A),
// cvt_pk epilogue. No LDS / barriers / waitcnt asm in the loop.
__global__ __launch_bounds__(512, 2) void opm_kernel(
    const unsigned short* __restrict__ Atf, const unsigned short* __restrict__ Btf,
    const unsigned short* __restrict__ w3frag, const float* __restrict__ b3,
    float* __restrict__ Z)
{
    __shared__ alignas(128) char smem[131072];         // epilogue op tile only

    const int tid = threadIdx.x, wv = tid >> 6, lane = tid & 63;

    // XCD-aware remap: 2304 blocks; XCD owns 6-i-tile band x all j (j-major walk)
    const int lin = blockIdx.x;
    const int xcd = lin & 7, chunk = lin >> 3;         // chunk in [0,288)
    const int i0 = (xcd * 6 + (chunk % 6)) * 256;
    const int j0 = (chunk / 6) * 256;

    const int lrow = lane & 15;
    const int wr = (wv >> 2) * 128, wc = (wv & 3) * 64;
    // scalarized fragment bases: provably wave-uniform -> saddr-form loads
    const int fa0 = __builtin_amdgcn_readfirstlane((i0 + wr) >> 4);
    const int fb0 = __builtin_amdgcn_readfirstlane((j0 + wc) >> 4);

    f32x4 acc[8][4] = {};
    bf16x8 av0[8], bv0[4], av1[8], bv1[4];

    auto loadSet = [&](bf16x8* av, bf16x8* bv, int s) {   // s = kc (half-K-tile)
        #pragma unroll
        for (int mf = 0; mf < 8; ++mf)
            av[mf] = *(const bf16x8*)(Atf + (size_t)((fa0 + mf) * 16 + s) * 512 + lane * 8);
        #pragma unroll
        for (int nf = 0; nf < 4; ++nf)
            bv[nf] = __builtin_nontemporal_load(
                (const bf16x8*)(Btf + (size_t)((fb0 + nf) * 16 + s) * 512 + lane * 8));
    };
    auto mmSet = [&](bf16x8* av, bf16x8* bv) {
        PRIO1();
        #pragma unroll
        for (int mf = 0; mf < 8; ++mf)
            #pragma unroll
            for (int nf = 0; nf < 4; ++nf)
                acc[mf][nf] = __builtin_amdgcn_mfma_f32_16x16x32_bf16(
                    av[mf], bv[nf], acc[mf][nf], 0, 0, 0);
        PRIO0();
    };

    // prologue: fill ring-2
    loadSet(av0, bv0, 0);
    loadSet(av1, bv1, 1);

    // 16 half-K-tile steps, fully unrolled; no synchronization of any kind
    #pragma unroll
    for (int s = 0; s < 16; ++s) {
        bf16x8* av = (s & 1) ? av1 : av0;
        bf16x8* bv = (s & 1) ? bv1 : bv0;
        mmSet(av, bv);                                  // auto-vmcnt waits set s
        if (s + 2 < 16) loadSet(av, bv, s + 2);         // refill freed set
    }

    // ---- fused w3 epilogue (R11/R12-verified layout) ----
    char* const opb = smem;                            // 64 pairs x 2048 B
    const int pfb = (wv >> 2) * 2;
    const int zgb = __builtin_amdgcn_readfirstlane((wv & 3) * 2);  // saddr-form ldW
    const int row0 = pfb * 16 + lrow, row1 = row0 + 16;
    const int lq = lane >> 4;

    auto ldW = [&](int ks, int zg) -> bf16x8 {
        return *(const bf16x8*)(w3frag + (size_t)((ks * 8 + zg) * 64 + lane) * 8);
    };
    auto ldP = [&](int row, int ks) -> bf16x8 {
        int g = ks * 4 + lq;
        int b = g >> 2, jj = g & 3;
        int inner = (b * 64 + jj * 16) ^ (((b >> 1) & 7) << 4) ^ ((row & 7) << 4);
        return *(const bf16x8*)(opb + row * 2048 + inner);
    };

    // early-issue first w3 loads (hide under op-write)
    bf16x8 wA0 = ldW(0, zgb), wA1 = ldW(0, zgb + 1);
    bf16x8 wB0 = ldW(1, zgb), wB1 = ldW(1, zgb + 1);

    // write op tile (scaled, bf16), b-major k2' = b*32+a, 8B vector stores,
    // packed via v_cvt_pk_bf16_f32 (2 converts / instruction)
    const float scale = 1.0f / (float)NB;
    #pragma unroll
    for (int mf = 0; mf < 8; ++mf) {
        #pragma unroll
        for (int nf = 0; nf < 4; ++nf) {
            int col = wc + nf * 16 + lrow;
            int bcol = col & 31;
            int row = wr + mf * 16 + ((lane >> 4) << 2);
            int pl = ((row >> 5) << 3) | (col >> 5);
            int a0e = row & 31;
            int inner = (bcol * 64 + a0e * 2) ^ (((bcol >> 1) & 7) << 4) ^ ((pl & 7) << 4);
            uint2 pk;
            pk.x = cvtpk(acc[mf][nf][0] * scale, acc[mf][nf][1] * scale);
            pk.y = cvtpk(acc[mf][nf][2] * scale, acc[mf][nf][3] * scale);
            *(uint2*)(opb + pl * 2048 + inner) = pk;
        }
    }
    __syncthreads();

    // z-loop: 2-deep software pipeline (w3 from L2, op from LDS)
    f32x4 acc2[2][2] = {};
    bf16x8 pA0 = ldP(row0, 0), pA1 = ldP(row1, 0);
    bf16x8 pB0 = ldP(row0, 1), pB1 = ldP(row1, 1);
    for (int ks = 0; ks < 32; ks += 2) {
        bf16x8 wN0 = {}, wN1 = {}, pN0 = {}, pN1 = {};
        bf16x8 wM0 = {}, wM1 = {}, pM0 = {}, pM1 = {};
        if (ks + 2 < 32) {
            wN0 = ldW(ks + 2, zgb); wN1 = ldW(ks + 2, zgb + 1);
            pN0 = ldP(row0, ks + 2); pN1 = ldP(row1, ks + 2);
            wM0 = ldW(ks + 3, zgb); wM1 = ldW(ks + 3, zgb + 1);
            pM0 = ldP(row0, ks + 3); pM1 = ldP(row1, ks + 3);
        }
        PRIO1();
        acc2[0][0] = __builtin_amdgcn_mfma_f32_16x16x32_bf16(pA0, wA0, acc2[0][0], 0, 0, 0);
        acc2[0][1] = __builtin_amdgcn_mfma_f32_16x16x32_bf16(pA0, wA1, acc2[0][1], 0, 0, 0);
        acc2[1][0] = __builtin_amdgcn_mfma_f32_16x16x32_bf16(pA1, wA0, acc2[1][0], 0, 0, 0);
        acc2[1][1] = __builtin_amdgcn_mfma_f32_16x16x32_bf16(pA1, wA1, acc2[1][1], 0, 0, 0);
        acc2[0][0] = __builtin_amdgcn_mfma_f32_16x16x32_bf16(pB0, wB0, acc2[0][0], 0, 0, 0);
        acc2[0][1] = __builtin_amdgcn_mfma_f32_16x16x32_bf16(pB0, wB1, acc2[0][1], 0, 0, 0);
        acc2[1][0] = __builtin_amdgcn_mfma_f32_16x16x32_bf16(pB1, wB0, acc2[1][0], 0, 0, 0);
        acc2[1][1] = __builtin_amdgcn_mfma_f32_16x16x32_bf16(pB1, wB1, acc2[1][1], 0, 0, 0);
        PRIO0();
        wA0 = wN0; wA1 = wN1; pA0 = pN0; pA1 = pN1;
        wB0 = wM0; wB1 = wM1; pB0 = pM0; pB1 = pM1;
    }

    // write z
    const int pq = (lane >> 4) << 2;
    #pragma unroll
    for (int p = 0; p < 2; ++p) {
        #pragma unroll
        for (int zi = 0; zi < 2; ++zi) {
            int zc = (zgb + zi) * 16 + lrow;
            float bias = b3[zc];
            #pragma unroll
            for (int rr = 0; rr < 4; ++rr) {
                int pl = (pfb + p) * 16 + pq + rr;
                int ii = (i0 >> 5) + (pl >> 3);
                int jj = (j0 >> 5) + (pl & 7);
                Z[((size_t)ii * L_DIM + jj) * ZD + zc] = acc2[p][zi][rr] + bias;
            }
        }
    }
}

// ---------------------------------------------------------------------------
extern "C" void kernel_launch(void* const* d_in, const int* in_sizes, int n_in,
                              void* d_out, int out_size, void* d_ws, size_t ws_size,
                              hipStream_t stream)
{
    const float* mm    = (const float*)d_in[0];
    const float* gamma = (const float*)d_in[1];
    const float* beta  = (const float*)d_in[2];
    const float* w1    = (const float*)d_in[3];
    const float* b1    = (const float*)d_in[4];
    const float* w2    = (const float*)d_in[5];
    const float* b2    = (const float*)d_in[6];
    const float* w3    = (const float*)d_in[7];
    const float* b3    = (const float*)d_in[8];

    unsigned short* At     = (unsigned short*)d_ws;                  // frag order
    unsigned short* Bt     = At + (size_t)MROWS * NB;                // frag order
    unsigned short* w3frag = Bt + (size_t)MROWS * NB;                // 131072
    unsigned short* wfrag  = w3frag + 131072;                        // 16384

    prep_kernel<<<576, 256, 0, stream>>>(w1, w2, w3, w3frag, wfrag);
    ln_proj_kernel<<<dim3(16, 192), 256, 0, stream>>>(mm, gamma, beta, wfrag, b1, b2, At, Bt);
    opm_kernel<<<2304, 512, 0, stream>>>(At, Bt, w3frag, b3, (float*)d_out);
}

// Round 16
// 238.879 us; speedup vs baseline: 1.1309x; 1.1309x over previous
//
#include <hip/hip_runtime.h>
#include <hip/hip_bf16.h>
#include <stdint.h>

#define L_DIM 384
#define MD    256      // M_DIM
#define CC    32       // C
#define ZD    128      // Z_DIM
#define NB    512      // N (batch) = K of the big GEMM
#define K2    1024     // C*C
#define MROWS 12288    // L*C

typedef __attribute__((ext_vector_type(4)))  float f32x4;
typedef __attribute__((ext_vector_type(8)))  short bf16x8;

#define PRIO1() __builtin_amdgcn_s_setprio(1)
#define PRIO0() __builtin_amdgcn_s_setprio(0)

__device__ __forceinline__ unsigned short f2bf(float x) {
    union { float f; unsigned u; } v; v.f = x;
    unsigned r = v.u + 0x7fffu + ((v.u >> 16) & 1u);   // round-to-nearest-even
    return (unsigned short)(r >> 16);
}

__device__ __forceinline__ uint2 pack4(unsigned short a, unsigned short b,
                                       unsigned short c, unsigned short d) {
    uint2 r; r.x = (unsigned)a | ((unsigned)b << 16);
    r.y = (unsigned)c | ((unsigned)d << 16); return r;
}

// HW packed f32->bf16 (RNE): 2 converts in 1 instruction
__device__ __forceinline__ unsigned cvtpk(float lo, float hi) {
    unsigned r;
    asm("v_cvt_pk_bf16_f32 %0, %1, %2" : "=v"(r) : "v"(lo), "v"(hi));
    return r;
}

// ---------------------------------------------------------------------------
// prep: w3 -> MFMA B-fragment order w3frag[ks][zg][lane][8], k2' = b*32+a
// (b-major so op tile writes vectorize). w1/w2 -> wfrag for ln_proj.
__global__ __launch_bounds__(256) void prep_kernel(
    const float* __restrict__ w1, const float* __restrict__ w2,
    const float* __restrict__ w3,
    unsigned short* __restrict__ w3frag, unsigned short* __restrict__ wfrag)
{
    int idx = blockIdx.x * 256 + threadIdx.x;          // 147456 total
    if (idx < 131072) {
        int e = idx & 7, lane = (idx >> 3) & 63, zg = (idx >> 9) & 7, ks = idx >> 12;
        int k2p = ks * 32 + ((lane >> 4) << 3) + e;    // k2' = b*32 + a
        int wrow = (k2p & 31) * 32 + (k2p >> 5);       // = a*32 + b
        int z  = zg * 16 + (lane & 15);
        w3frag[idx] = f2bf(w3[(size_t)wrow * ZD + z]);
    } else {
        int j = idx - 131072;                           // 16384
        int e = j & 7, lane = (j >> 3) & 63, nf = (j >> 9) & 3, ks = j >> 11;
        int c = nf * 16 + (lane & 15);
        int d = ks * 32 + ((lane >> 4) << 3) + e;
        float v = (c < CC) ? w2[d * CC + c] : w1[d * CC + (c - CC)];
        wfrag[j] = f2bf(v);
    }
}

// ---------------------------------------------------------------------------
// Kernel A: LayerNorm + dual projection via MFMA.
// BOTH At and Bt written in 16x16-MFMA fragment order [frag][kc][lane][8]
// (R6/R12-verified layout): frag = row/16, lane = (row&15) + 16*((n>>3)&3),
// elem = n&7, kc = n>>5.
__global__ __launch_bounds__(256, 4) void ln_proj_kernel(
    const float* __restrict__ mm, const float* __restrict__ gamma, const float* __restrict__ beta,
    const unsigned short* __restrict__ wfrag,
    const float* __restrict__ b1, const float* __restrict__ b2,
    unsigned short* __restrict__ At, unsigned short* __restrict__ Bt)
{
    __shared__ alignas(16) char o_b[32768];            // [64 rows][512 B] swizzled

    const int tid = threadIdx.x, wv = tid >> 6, lane = tid & 63;
    const int l0 = blockIdx.y * 2;
    const int n0 = blockIdx.x * 32;

    const int l_loc = wv >> 1;
    const int nbase = (wv & 1) << 4;
    const int l_g = l0 + l_loc;
    f32x4 g4 = *(const f32x4*)(gamma + lane * 4);
    f32x4 e4 = *(const f32x4*)(beta + lane * 4);

    #pragma unroll 4
    for (int r = 0; r < 16; ++r) {
        int row_loc = wv * 16 + r;
        int n_g = n0 + nbase + r;
        const float* src = mm + ((size_t)n_g * L_DIM + l_g) * MD + lane * 4;
        f32x4 x = *(const f32x4*)src;
        float s  = x[0] + x[1] + x[2] + x[3];
        float s2 = x[0]*x[0] + x[1]*x[1] + x[2]*x[2] + x[3]*x[3];
        #pragma unroll
        for (int off = 32; off > 0; off >>= 1) {
            s  += __shfl_xor(s,  off);
            s2 += __shfl_xor(s2, off);
        }
        float mu  = s * (1.0f / MD);
        float var = s2 * (1.0f / MD) - mu * mu;
        float rs  = rsqrtf(var + 1e-5f);
        unsigned short o0 = f2bf((x[0] - mu) * rs * g4[0] + e4[0]);
        unsigned short o1 = f2bf((x[1] - mu) * rs * g4[1] + e4[1]);
        unsigned short o2 = f2bf((x[2] - mu) * rs * g4[2] + e4[2]);
        unsigned short o3 = f2bf((x[3] - mu) * rs * g4[3] + e4[3]);
        *(uint2*)(o_b + row_loc * 512 + ((lane * 8) ^ ((row_loc & 7) << 4))) = pack4(o0, o1, o2, o3);
    }
    // wave-private rows -> no barrier needed

    f32x4 acc[4] = {{0,0,0,0},{0,0,0,0},{0,0,0,0},{0,0,0,0}};
    const int lrow = lane & 15;
    const int kq16 = (lane >> 4) << 4;
    const int arow = wv * 16 + lrow;
    #pragma unroll
    for (int ks = 0; ks < 8; ++ks) {
        bf16x8 a = *(const bf16x8*)(o_b + arow * 512 + ((ks * 64 + kq16) ^ ((arow & 7) << 4)));
        #pragma unroll
        for (int nf = 0; nf < 4; ++nf) {
            bf16x8 b = *(const bf16x8*)(wfrag + (size_t)((ks * 4 + nf) * 64 + lane) * 8);
            acc[nf] = __builtin_amdgcn_mfma_f32_16x16x32_bf16(a, b, acc[nf], 0, 0, 0);
        }
    }

    const int rr0 = wv * 16 + ((lane >> 4) << 2);
    const int n_gw = n0 + (rr0 & 31);
    const int l_gw = l0 + (rr0 >> 5);
    #pragma unroll
    for (int nf = 0; nf < 4; ++nf) {
        int c = nf * 16 + lrow;
        float bias = (c < CC) ? b2[c] : b1[c - CC];
        uint2 pk = pack4(f2bf(acc[nf][0] + bias), f2bf(acc[nf][1] + bias),
                         f2bf(acc[nf][2] + bias), f2bf(acc[nf][3] + bias));
        int c31 = c & 31;
        int f = l_gw * 2 + (c31 >> 4);                 // fragment index (row/16)
        int lanep = (c31 & 15) + (((n_gw >> 3) & 3) << 4);
        size_t addr = ((size_t)(f * 16 + (n_gw >> 5)) * 64 + lanep) * 8 + (n_gw & 7);
        *(uint2*)(((c < CC) ? At : Bt) + addr) = pk;
    }
}

// ---------------------------------------------------------------------------
// Kernel B: 256x256 op-tile GEMM, ZERO-SYNC main loop (R12/R14 winner):
// saddr-form loads (readfirstlane bases), plain B loads (R15's nontemporal
// reverted: it evicted B from L2, +28MB HBM), cvt_pk epilogue pack.
// Epilogue: one-zg-per-wave (R9-verified) -> w3 L2 traffic halved to the
// 256KB/block minimum; ring-4 w3 + ring-2 P static register pipelines.
__global__ __launch_bounds__(512, 2) void opm_kernel(
    const unsigned short* __restrict__ Atf, const unsigned short* __restrict__ Btf,
    const unsigned short* __restrict__ w3frag, const float* __restrict__ b3,
    float* __restrict__ Z)
{
    __shared__ alignas(128) char smem[131072];         // epilogue op tile only

    const int tid = threadIdx.x, wv = tid >> 6, lane = tid & 63;

    // XCD-aware remap: 2304 blocks; XCD owns 6-i-tile band x all j (j-major walk)
    const int lin = blockIdx.x;
    const int xcd = lin & 7, chunk = lin >> 3;         // chunk in [0,288)
    const int i0 = (xcd * 6 + (chunk % 6)) * 256;
    const int j0 = (chunk / 6) * 256;

    const int lrow = lane & 15;
    const int wr = (wv >> 2) * 128, wc = (wv & 3) * 64;
    // scalarized fragment bases: provably wave-uniform -> saddr-form loads
    const int fa0 = __builtin_amdgcn_readfirstlane((i0 + wr) >> 4);
    const int fb0 = __builtin_amdgcn_readfirstlane((j0 + wc) >> 4);

    f32x4 acc[8][4] = {};
    bf16x8 av0[8], bv0[4], av1[8], bv1[4];

    auto loadSet = [&](bf16x8* av, bf16x8* bv, int s) {   // s = kc (half-K-tile)
        #pragma unroll
        for (int mf = 0; mf < 8; ++mf)
            av[mf] = *(const bf16x8*)(Atf + (size_t)((fa0 + mf) * 16 + s) * 512 + lane * 8);
        #pragma unroll
        for (int nf = 0; nf < 4; ++nf)
            bv[nf] = *(const bf16x8*)(Btf + (size_t)((fb0 + nf) * 16 + s) * 512 + lane * 8);
    };
    auto mmSet = [&](bf16x8* av, bf16x8* bv) {
        PRIO1();
        #pragma unroll
        for (int mf = 0; mf < 8; ++mf)
            #pragma unroll
            for (int nf = 0; nf < 4; ++nf)
                acc[mf][nf] = __builtin_amdgcn_mfma_f32_16x16x32_bf16(
                    av[mf], bv[nf], acc[mf][nf], 0, 0, 0);
        PRIO0();
    };

    // prologue: fill ring-2
    loadSet(av0, bv0, 0);
    loadSet(av1, bv1, 1);

    // 16 half-K-tile steps, fully unrolled; no synchronization of any kind
    #pragma unroll
    for (int s = 0; s < 16; ++s) {
        bf16x8* av = (s & 1) ? av1 : av0;
        bf16x8* bv = (s & 1) ? bv1 : bv0;
        mmSet(av, bv);                                  // auto-vmcnt waits set s
        if (s + 2 < 16) loadSet(av, bv, s + 2);         // refill freed set
    }

    // ---- fused w3 epilogue: one zg per wave (min w3 L2), ring-4 w3 + ring-2 P
    char* const opb = smem;                            // 64 pairs x 2048 B
    const int lq = lane >> 4;
    const int zg = __builtin_amdgcn_readfirstlane(wv); // zg = wave -> 1x w3 traffic
    const int zc = zg * 16 + lrow;

    auto ldW = [&](int ks) -> bf16x8 {
        return *(const bf16x8*)(w3frag + (size_t)((ks * 8 + zg) * 64 + lane) * 8);
    };
    auto ldP = [&](int rg, int ks) -> bf16x8 {
        int row = rg * 16 + lrow;
        int g = ks * 4 + lq;
        int b = g >> 2, jj = g & 3;
        int inner = (b * 64 + jj * 16) ^ (((b >> 1) & 7) << 4) ^ ((row & 7) << 4);
        return *(const bf16x8*)(opb + row * 2048 + inner);
    };

    // early-issue ring-4 w3 loads (L2 latency hides under op-write + sync)
    bf16x8 wR0 = ldW(0), wR1 = ldW(1), wR2 = ldW(2), wR3 = ldW(3);

    // write op tile (scaled, bf16), b-major k2' = b*32+a, 8B vector stores,
    // packed via v_cvt_pk_bf16_f32 (2 converts / instruction)
    const float scale = 1.0f / (float)NB;
    #pragma unroll
    for (int mf = 0; mf < 8; ++mf) {
        #pragma unroll
        for (int nf = 0; nf < 4; ++nf) {
            int col = wc + nf * 16 + lrow;
            int bcol = col & 31;
            int row = wr + mf * 16 + ((lane >> 4) << 2);
            int pl = ((row >> 5) << 3) | (col >> 5);
            int a0e = row & 31;
            int inner = (bcol * 64 + a0e * 2) ^ (((bcol >> 1) & 7) << 4) ^ ((pl & 7) << 4);
            uint2 pk;
            pk.x = cvtpk(acc[mf][nf][0] * scale, acc[mf][nf][1] * scale);
            pk.y = cvtpk(acc[mf][nf][2] * scale, acc[mf][nf][3] * scale);
            *(uint2*)(opb + pl * 2048 + inner) = pk;
        }
    }
    __syncthreads();

    // z-loop: 32 ks; per ks: 4 P-frag LDS reads (ring-2) + 1 w3 read (ring-4)
    // + 4 MFMA. Fully unrolled -> all ring indices static (no scratch).
    f32x4 accP[4] = {};
    bf16x8 pA[4], pB[4];
    #pragma unroll
    for (int r = 0; r < 4; ++r) pA[r] = ldP(r, 0);
    #pragma unroll
    for (int r = 0; r < 4; ++r) pB[r] = ldP(r, 1);

    #pragma unroll
    for (int ks = 0; ks < 32; ++ks) {
        bf16x8 w = ((ks & 3) == 0) ? wR0 : ((ks & 3) == 1) ? wR1
                 : ((ks & 3) == 2) ? wR2 : wR3;
        bf16x8* pc = (ks & 1) ? pB : pA;
        PRIO1();
        accP[0] = __builtin_amdgcn_mfma_f32_16x16x32_bf16(pc[0], w, accP[0], 0, 0, 0);
        accP[1] = __builtin_amdgcn_mfma_f32_16x16x32_bf16(pc[1], w, accP[1], 0, 0, 0);
        accP[2] = __builtin_amdgcn_mfma_f32_16x16x32_bf16(pc[2], w, accP[2], 0, 0, 0);
        accP[3] = __builtin_amdgcn_mfma_f32_16x16x32_bf16(pc[3], w, accP[3], 0, 0, 0);
        PRIO0();
        if (ks + 4 < 32) {
            if ((ks & 3) == 0)      wR0 = ldW(ks + 4);
            else if ((ks & 3) == 1) wR1 = ldW(ks + 4);
            else if ((ks & 3) == 2) wR2 = ldW(ks + 4);
            else                    wR3 = ldW(ks + 4);
        }
        if (ks + 2 < 32) {
            #pragma unroll
            for (int r = 0; r < 4; ++r) pc[r] = ldP(r, ks + 2);
        }
    }

    // write z
    const int pq = (lane >> 4) << 2;
    const float bias = b3[zc];
    #pragma unroll
    for (int pf = 0; pf < 4; ++pf) {
        #pragma unroll
        for (int rr = 0; rr < 4; ++rr) {
            int pl = pf * 16 + pq + rr;
            int ii = (i0 >> 5) + (pl >> 3);
            int jj = (j0 >> 5) + (pl & 7);
            Z[((size_t)ii * L_DIM + jj) * ZD + zc] = accP[pf][rr] + bias;
        }
    }
}

// ---------------------------------------------------------------------------
extern "C" void kernel_launch(void* const* d_in, const int* in_sizes, int n_in,
                              void* d_out, int out_size, void* d_ws, size_t ws_size,
                              hipStream_t stream)
{
    const float* mm    = (const float*)d_in[0];
    const float* gamma = (const float*)d_in[1];
    const float* beta  = (const float*)d_in[2];
    const float* w1    = (const float*)d_in[3];
    const float* b1    = (const float*)d_in[4];
    const float* w2    = (const float*)d_in[5];
    const float* b2    = (const float*)d_in[6];
    const float* w3    = (const float*)d_in[7];
    const float* b3    = (const float*)d_in[8];

    unsigned short* At     = (unsigned short*)d_ws;                  // frag order
    unsigned short* Bt     = At + (size_t)MROWS * NB;                // frag order
    unsigned short* w3frag = Bt + (size_t)MROWS * NB;                // 131072
    unsigned short* wfrag  = w3frag + 131072;                        // 16384

    prep_kernel<<<576, 256, 0, stream>>>(w1, w2, w3, w3frag, wfrag);
    ln_proj_kernel<<<dim3(16, 192), 256, 0, stream>>>(mm, gamma, beta, wfrag, b1, b2, At, Bt);
    opm_kernel<<<2304, 512, 0, stream>>>(At, Bt, w3frag, b3, (float*)d_out);
}

// Round 17
// 233.727 us; speedup vs baseline: 1.1558x; 1.0220x over previous
//
#include <hip/hip_runtime.h>
#include <hip/hip_bf16.h>
#include <stdint.h>

#define L_DIM 384
#define MD    256      // M_DIM
#define CC    32       // C
#define ZD    128      // Z_DIM
#define NB    512      // N (batch) = K of the big GEMM
#define K2    1024     // C*C
#define MROWS 12288    // L*C
#define NFRG  768      // MROWS/16 fragments per operand per kc

typedef __attribute__((ext_vector_type(4)))  float f32x4;
typedef __attribute__((ext_vector_type(8)))  short bf16x8;

#define PRIO1() __builtin_amdgcn_s_setprio(1)
#define PRIO0() __builtin_amdgcn_s_setprio(0)

__device__ __forceinline__ unsigned short f2bf(float x) {
    union { float f; unsigned u; } v; v.f = x;
    unsigned r = v.u + 0x7fffu + ((v.u >> 16) & 1u);   // round-to-nearest-even
    return (unsigned short)(r >> 16);
}

__device__ __forceinline__ uint2 pack4(unsigned short a, unsigned short b,
                                       unsigned short c, unsigned short d) {
    uint2 r; r.x = (unsigned)a | ((unsigned)b << 16);
    r.y = (unsigned)c | ((unsigned)d << 16); return r;
}

// HW packed f32->bf16 (RNE): 2 converts in 1 instruction
__device__ __forceinline__ unsigned cvtpk(float lo, float hi) {
    unsigned r;
    asm("v_cvt_pk_bf16_f32 %0, %1, %2" : "=v"(r) : "v"(lo), "v"(hi));
    return r;
}

// ---------------------------------------------------------------------------
// prep: w3 -> MFMA B-fragment order w3frag[ks][zg][lane][8], k2' = b*32+a
// (b-major so op tile writes vectorize). w1/w2 -> wfrag for ln_proj.
__global__ __launch_bounds__(256) void prep_kernel(
    const float* __restrict__ w1, const float* __restrict__ w2,
    const float* __restrict__ w3,
    unsigned short* __restrict__ w3frag, unsigned short* __restrict__ wfrag)
{
    int idx = blockIdx.x * 256 + threadIdx.x;          // 147456 total
    if (idx < 131072) {
        int e = idx & 7, lane = (idx >> 3) & 63, zg = (idx >> 9) & 7, ks = idx >> 12;
        int k2p = ks * 32 + ((lane >> 4) << 3) + e;    // k2' = b*32 + a
        int wrow = (k2p & 31) * 32 + (k2p >> 5);       // = a*32 + b
        int z  = zg * 16 + (lane & 15);
        w3frag[idx] = f2bf(w3[(size_t)wrow * ZD + z]);
    } else {
        int j = idx - 131072;                           // 16384
        int e = j & 7, lane = (j >> 3) & 63, nf = (j >> 9) & 3, ks = j >> 11;
        int c = nf * 16 + (lane & 15);
        int d = ks * 32 + ((lane >> 4) << 3) + e;
        float v = (c < CC) ? w2[d * CC + c] : w1[d * CC + (c - CC)];
        wfrag[j] = f2bf(v);
    }
}

// ---------------------------------------------------------------------------
// Kernel A: LayerNorm + dual projection via MFMA.
// BOTH At and Bt written in kc-MAJOR 16x16-MFMA fragment order
// [kc][frag][lane][8]: for each K-step kc, the 768 fragments are contiguous
// 1KB blocks (no 16KB power-of-2 stride -> no L1 set aliasing in opm).
// Inner mapping unchanged (R6/R12-verified): frag = row/16,
// lane = (row&15) + 16*((n>>3)&3), elem = n&7, kc = n>>5.
__global__ __launch_bounds__(256, 4) void ln_proj_kernel(
    const float* __restrict__ mm, const float* __restrict__ gamma, const float* __restrict__ beta,
    const unsigned short* __restrict__ wfrag,
    const float* __restrict__ b1, const float* __restrict__ b2,
    unsigned short* __restrict__ At, unsigned short* __restrict__ Bt)
{
    __shared__ alignas(16) char o_b[32768];            // [64 rows][512 B] swizzled

    const int tid = threadIdx.x, wv = tid >> 6, lane = tid & 63;
    const int l0 = blockIdx.y * 2;
    const int n0 = blockIdx.x * 32;

    const int l_loc = wv >> 1;
    const int nbase = (wv & 1) << 4;
    const int l_g = l0 + l_loc;
    f32x4 g4 = *(const f32x4*)(gamma + lane * 4);
    f32x4 e4 = *(const f32x4*)(beta + lane * 4);

    #pragma unroll 4
    for (int r = 0; r < 16; ++r) {
        int row_loc = wv * 16 + r;
        int n_g = n0 + nbase + r;
        const float* src = mm + ((size_t)n_g * L_DIM + l_g) * MD + lane * 4;
        f32x4 x = *(const f32x4*)src;
        float s  = x[0] + x[1] + x[2] + x[3];
        float s2 = x[0]*x[0] + x[1]*x[1] + x[2]*x[2] + x[3]*x[3];
        #pragma unroll
        for (int off = 32; off > 0; off >>= 1) {
            s  += __shfl_xor(s,  off);
            s2 += __shfl_xor(s2, off);
        }
        float mu  = s * (1.0f / MD);
        float var = s2 * (1.0f / MD) - mu * mu;
        float rs  = rsqrtf(var + 1e-5f);
        unsigned short o0 = f2bf((x[0] - mu) * rs * g4[0] + e4[0]);
        unsigned short o1 = f2bf((x[1] - mu) * rs * g4[1] + e4[1]);
        unsigned short o2 = f2bf((x[2] - mu) * rs * g4[2] + e4[2]);
        unsigned short o3 = f2bf((x[3] - mu) * rs * g4[3] + e4[3]);
        *(uint2*)(o_b + row_loc * 512 + ((lane * 8) ^ ((row_loc & 7) << 4))) = pack4(o0, o1, o2, o3);
    }
    // wave-private rows -> no barrier needed

    f32x4 acc[4] = {{0,0,0,0},{0,0,0,0},{0,0,0,0},{0,0,0,0}};
    const int lrow = lane & 15;
    const int kq16 = (lane >> 4) << 4;
    const int arow = wv * 16 + lrow;
    #pragma unroll
    for (int ks = 0; ks < 8; ++ks) {
        bf16x8 a = *(const bf16x8*)(o_b + arow * 512 + ((ks * 64 + kq16) ^ ((arow & 7) << 4)));
        #pragma unroll
        for (int nf = 0; nf < 4; ++nf) {
            bf16x8 b = *(const bf16x8*)(wfrag + (size_t)((ks * 4 + nf) * 64 + lane) * 8);
            acc[nf] = __builtin_amdgcn_mfma_f32_16x16x32_bf16(a, b, acc[nf], 0, 0, 0);
        }
    }

    const int rr0 = wv * 16 + ((lane >> 4) << 2);
    const int n_gw = n0 + (rr0 & 31);
    const int l_gw = l0 + (rr0 >> 5);
    #pragma unroll
    for (int nf = 0; nf < 4; ++nf) {
        int c = nf * 16 + lrow;
        float bias = (c < CC) ? b2[c] : b1[c - CC];
        uint2 pk = pack4(f2bf(acc[nf][0] + bias), f2bf(acc[nf][1] + bias),
                         f2bf(acc[nf][2] + bias), f2bf(acc[nf][3] + bias));
        int c31 = c & 31;
        int f = l_gw * 2 + (c31 >> 4);                 // fragment index (row/16)
        int lanep = (c31 & 15) + (((n_gw >> 3) & 3) << 4);
        // kc-major: [kc=n>>5][frag][lane][elem]
        size_t addr = ((size_t)((n_gw >> 5) * NFRG + f) * 64 + lanep) * 8 + (n_gw & 7);
        *(uint2*)(((c < CC) ? At : Bt) + addr) = pk;
    }
}

// ---------------------------------------------------------------------------
// Kernel B: 256x256 op-tile GEMM, ZERO-SYNC main loop (R12/R14/R16 winner):
// saddr-form loads (readfirstlane bases), kc-major fragment layout (per-step
// operand spans are contiguous 16KB -> no L1 set aliasing), cvt_pk epilogue,
// one-zg-per-wave w3 epilogue. No LDS / barriers / waitcnt asm in the loop.
__global__ __launch_bounds__(512, 2) void opm_kernel(
    const unsigned short* __restrict__ Atf, const unsigned short* __restrict__ Btf,
    const unsigned short* __restrict__ w3frag, const float* __restrict__ b3,
    float* __restrict__ Z)
{
    __shared__ alignas(128) char smem[131072];         // epilogue op tile only

    const int tid = threadIdx.x, wv = tid >> 6, lane = tid & 63;

    // XCD-aware remap: 2304 blocks; XCD owns 6-i-tile band x all j (j-major walk)
    const int lin = blockIdx.x;
    const int xcd = lin & 7, chunk = lin >> 3;         // chunk in [0,288)
    const int i0 = (xcd * 6 + (chunk % 6)) * 256;
    const int j0 = (chunk / 6) * 256;

    const int lrow = lane & 15;
    const int wr = (wv >> 2) * 128, wc = (wv & 3) * 64;
    // scalarized fragment bases: provably wave-uniform -> saddr-form loads
    const int fa0 = __builtin_amdgcn_readfirstlane((i0 + wr) >> 4);
    const int fb0 = __builtin_amdgcn_readfirstlane((j0 + wc) >> 4);

    f32x4 acc[8][4] = {};
    bf16x8 av0[8], bv0[4], av1[8], bv1[4];

    auto loadSet = [&](bf16x8* av, bf16x8* bv, int s) {   // s = kc (half-K-tile)
        #pragma unroll
        for (int mf = 0; mf < 8; ++mf)
            av[mf] = *(const bf16x8*)(Atf + (size_t)(s * NFRG + fa0 + mf) * 512 + lane * 8);
        #pragma unroll
        for (int nf = 0; nf < 4; ++nf)
            bv[nf] = *(const bf16x8*)(Btf + (size_t)(s * NFRG + fb0 + nf) * 512 + lane * 8);
    };
    auto mmSet = [&](bf16x8* av, bf16x8* bv) {
        PRIO1();
        #pragma unroll
        for (int mf = 0; mf < 8; ++mf)
            #pragma unroll
            for (int nf = 0; nf < 4; ++nf)
                acc[mf][nf] = __builtin_amdgcn_mfma_f32_16x16x32_bf16(
                    av[mf], bv[nf], acc[mf][nf], 0, 0, 0);
        PRIO0();
    };

    // prologue: fill ring-2
    loadSet(av0, bv0, 0);
    loadSet(av1, bv1, 1);

    // 16 half-K-tile steps, fully unrolled; no synchronization of any kind
    #pragma unroll
    for (int s = 0; s < 16; ++s) {
        bf16x8* av = (s & 1) ? av1 : av0;
        bf16x8* bv = (s & 1) ? bv1 : bv0;
        mmSet(av, bv);                                  // auto-vmcnt waits set s
        if (s + 2 < 16) loadSet(av, bv, s + 2);         // refill freed set
    }

    // ---- fused w3 epilogue: one zg per wave (min w3 L2), ring-4 w3 + ring-2 P
    char* const opb = smem;                            // 64 pairs x 2048 B
    const int lq = lane >> 4;
    const int zg = __builtin_amdgcn_readfirstlane(wv); // zg = wave -> 1x w3 traffic
    const int zc = zg * 16 + lrow;

    auto ldW = [&](int ks) -> bf16x8 {
        return *(const bf16x8*)(w3frag + (size_t)((ks * 8 + zg) * 64 + lane) * 8);
    };
    auto ldP = [&](int rg, int ks) -> bf16x8 {
        int row = rg * 16 + lrow;
        int g = ks * 4 + lq;
        int b = g >> 2, jj = g & 3;
        int inner = (b * 64 + jj * 16) ^ (((b >> 1) & 7) << 4) ^ ((row & 7) << 4);
        return *(const bf16x8*)(opb + row * 2048 + inner);
    };

    // early-issue ring-4 w3 loads (L2 latency hides under op-write + sync)
    bf16x8 wR0 = ldW(0), wR1 = ldW(1), wR2 = ldW(2), wR3 = ldW(3);

    // write op tile (scaled, bf16), b-major k2' = b*32+a, 8B vector stores,
    // packed via v_cvt_pk_bf16_f32 (2 converts / instruction)
    const float scale = 1.0f / (float)NB;
    #pragma unroll
    for (int mf = 0; mf < 8; ++mf) {
        #pragma unroll
        for (int nf = 0; nf < 4; ++nf) {
            int col = wc + nf * 16 + lrow;
            int bcol = col & 31;
            int row = wr + mf * 16 + ((lane >> 4) << 2);
            int pl = ((row >> 5) << 3) | (col >> 5);
            int a0e = row & 31;
            int inner = (bcol * 64 + a0e * 2) ^ (((bcol >> 1) & 7) << 4) ^ ((pl & 7) << 4);
            uint2 pk;
            pk.x = cvtpk(acc[mf][nf][0] * scale, acc[mf][nf][1] * scale);
            pk.y = cvtpk(acc[mf][nf][2] * scale, acc[mf][nf][3] * scale);
            *(uint2*)(opb + pl * 2048 + inner) = pk;
        }
    }
    __syncthreads();

    // z-loop: 32 ks; per ks: 4 P-frag LDS reads (ring-2) + 1 w3 read (ring-4)
    // + 4 MFMA. Fully unrolled -> all ring indices static (no scratch).
    f32x4 accP[4] = {};
    bf16x8 pA[4], pB[4];
    #pragma unroll
    for (int r = 0; r < 4; ++r) pA[r] = ldP(r, 0);
    #pragma unroll
    for (int r = 0; r < 4; ++r) pB[r] = ldP(r, 1);

    #pragma unroll
    for (int ks = 0; ks < 32; ++ks) {
        bf16x8 w = ((ks & 3) == 0) ? wR0 : ((ks & 3) == 1) ? wR1
                 : ((ks & 3) == 2) ? wR2 : wR3;
        bf16x8* pc = (ks & 1) ? pB : pA;
        PRIO1();
        accP[0] = __builtin_amdgcn_mfma_f32_16x16x32_bf16(pc[0], w, accP[0], 0, 0, 0);
        accP[1] = __builtin_amdgcn_mfma_f32_16x16x32_bf16(pc[1], w, accP[1], 0, 0, 0);
        accP[2] = __builtin_amdgcn_mfma_f32_16x16x32_bf16(pc[2], w, accP[2], 0, 0, 0);
        accP[3] = __builtin_amdgcn_mfma_f32_16x16x32_bf16(pc[3], w, accP[3], 0, 0, 0);
        PRIO0();
        if (ks + 4 < 32) {
            if ((ks & 3) == 0)      wR0 = ldW(ks + 4);
            else if ((ks & 3) == 1) wR1 = ldW(ks + 4);
            else if ((ks & 3) == 2) wR2 = ldW(ks + 4);
            else                    wR3 = ldW(ks + 4);
        }
        if (ks + 2 < 32) {
            #pragma unroll
            for (int r = 0; r < 4; ++r) pc[r] = ldP(r, ks + 2);
        }
    }

    // write z
    const int pq = (lane >> 4) << 2;
    const float bias = b3[zc];
    #pragma unroll
    for (int pf = 0; pf < 4; ++pf) {
        #pragma unroll
        for (int rr = 0; rr < 4; ++rr) {
            int pl = pf * 16 + pq + rr;
            int ii = (i0 >> 5) + (pl >> 3);
            int jj = (j0 >> 5) + (pl & 7);
            Z[((size_t)ii * L_DIM + jj) * ZD + zc] = accP[pf][rr] + bias;
        }
    }
}

// ---------------------------------------------------------------------------
extern "C" void kernel_launch(void* const* d_in, const int* in_sizes, int n_in,
                              void* d_out, int out_size, void* d_ws, size_t ws_size,
                              hipStream_t stream)
{
    const float* mm    = (const float*)d_in[0];
    const float* gamma = (const float*)d_in[1];
    const float* beta  = (const float*)d_in[2];
    const float* w1    = (const float*)d_in[3];
    const float* b1    = (const float*)d_in[4];
    const float* w2    = (const float*)d_in[5];
    const float* b2    = (const float*)d_in[6];
    const float* w3    = (const float*)d_in[7];
    const float* b3    = (const float*)d_in[8];

    unsigned short* At     = (unsigned short*)d_ws;                  // kc-major frag order
    unsigned short* Bt     = At + (size_t)MROWS * NB;                // kc-major frag order
    unsigned short* w3frag = Bt + (size_t)MROWS * NB;                // 131072
    unsigned short* wfrag  = w3frag + 131072;                        // 16384

    prep_kernel<<<576, 256, 0, stream>>>(w1, w2, w3, w3frag, wfrag);
    ln_proj_kernel<<<dim3(16, 192), 256, 0, stream>>>(mm, gamma, beta, wfrag, b1, b2, At, Bt);
    opm_kernel<<<2304, 512, 0, stream>>>(At, Bt, w3frag, b3, (float*)d_out);
}